// Round 2
// baseline (118.372 us; speedup 1.0000x reference)
//
#include <hip/hip_runtime.h>
#include <math.h>

#define DIM   768
#define BATCH 4096
#define NQ    8
#define EPSLN 1e-5f

// ---------------------------------------------------------------------------
// Statevector layout: 9 wires, 512 amplitudes. amp index I = (lane << 3) | r.
//   wires 0..2  -> bits 0..2 of r (in-register, 8 complex amps per lane)
//   wires 3..8  -> bits 0..5 of lane
// One wave (64 lanes) simulates one batch row's circuit entirely in VGPRs.
// ---------------------------------------------------------------------------

__device__ __forceinline__ float shflx(float v, int m) { return __shfl_xor(v, m, 64); }

// RZ(theta): diag(e^{-i t/2}, e^{+i t/2}). Diagonal -> never needs a shuffle.
template<int W>
__device__ __forceinline__ void gate_rz(float (&re)[8], float (&im)[8],
                                        float c, float s, int lane) {
  if constexpr (W < 3) {
#pragma unroll
    for (int r = 0; r < 8; ++r) {
      const float t = ((r >> W) & 1) ? s : -s;   // compile-time after unroll
      const float xx = re[r], yy = im[r];
      re[r] = xx * c - yy * t;
      im[r] = yy * c + xx * t;
    }
  } else {
    const float t = ((lane >> (W - 3)) & 1) ? s : -s;  // uniform per lane
#pragma unroll
    for (int r = 0; r < 8; ++r) {
      const float xx = re[r], yy = im[r];
      re[r] = xx * c - yy * t;
      im[r] = yy * c + xx * t;
    }
  }
}

// RX(theta): [[c, -i s], [-i s, c]]
template<int W>
__device__ __forceinline__ void gate_rx(float (&re)[8], float (&im)[8],
                                        float c, float s) {
  if constexpr (W < 3) {
#pragma unroll
    for (int r = 0; r < 8; ++r) {
      if (!((r >> W) & 1)) {
        const int r2 = r | (1 << W);
        const float ar = re[r], ai = im[r], br = re[r2], bi = im[r2];
        re[r]  = c * ar + s * bi;
        im[r]  = c * ai - s * br;
        re[r2] = c * br + s * ai;
        im[r2] = c * bi - s * ar;
      }
    }
  } else {
    const int mask = 1 << (W - 3);
#pragma unroll
    for (int r = 0; r < 8; ++r) {
      const float ore = shflx(re[r], mask);
      const float oim = shflx(im[r], mask);
      const float xx = re[r], yy = im[r];
      // same formula on both sides of the pair (RX is symmetric)
      re[r] = c * xx + s * oim;
      im[r] = c * yy - s * ore;
    }
  }
}

// RY(theta): [[c, -s], [s, c]]
template<int W>
__device__ __forceinline__ void gate_ry(float (&re)[8], float (&im)[8],
                                        float c, float s, int lane) {
  if constexpr (W < 3) {
#pragma unroll
    for (int r = 0; r < 8; ++r) {
      if (!((r >> W) & 1)) {
        const int r2 = r | (1 << W);
        const float ar = re[r], ai = im[r], br = re[r2], bi = im[r2];
        re[r]  = c * ar - s * br;
        im[r]  = c * ai - s * bi;
        re[r2] = s * ar + c * br;
        im[r2] = s * ai + c * bi;
      }
    }
  } else {
    const int mask = 1 << (W - 3);
    const float t = ((lane >> (W - 3)) & 1) ? s : -s;  // lower half: c*a - s*b; upper: s*a + c*b
#pragma unroll
    for (int r = 0; r < 8; ++r) {
      const float ore = shflx(re[r], mask);
      const float oim = shflx(im[r], mask);
      re[r] = c * re[r] + t * ore;
      im[r] = c * im[r] + t * oim;
    }
  }
}

// CNOT(C, T): where control bit = 1, swap the target-bit pair.
template<int C, int T>
__device__ __forceinline__ void gate_cnot(float (&re)[8], float (&im)[8], int lane) {
  if constexpr (C < 3 && T < 3) {          // both local: pure register permute
#pragma unroll
    for (int r = 0; r < 8; ++r) {
      if (((r >> C) & 1) && !((r >> T) & 1)) {
        const int r2 = r | (1 << T);
        const float tr = re[r], ti = im[r];
        re[r] = re[r2]; im[r] = im[r2];
        re[r2] = tr;    im[r2] = ti;
      }
    }
  } else if constexpr (C < 3) {            // local control, lane target: shuffle-swap half
    const int mask = 1 << (T - 3);
#pragma unroll
    for (int r = 0; r < 8; ++r) {
      if ((r >> C) & 1) {
        re[r] = shflx(re[r], mask);
        im[r] = shflx(im[r], mask);
      }
    }
  } else if constexpr (T < 3) {            // lane control, local target: selects only
    const bool cc = (lane >> (C - 3)) & 1;
#pragma unroll
    for (int r = 0; r < 8; ++r) {
      if (!((r >> T) & 1)) {
        const int r2 = r | (1 << T);
        const float ar = re[r], ai = im[r], br = re[r2], bi = im[r2];
        re[r]  = cc ? br : ar;  im[r]  = cc ? bi : ai;
        re[r2] = cc ? ar : br;  im[r2] = cc ? ai : bi;
      }
    }
  } else {                                 // lane control, lane target: shuffle + select
    const int mask = 1 << (T - 3);
    const bool cc = (lane >> (C - 3)) & 1;
#pragma unroll
    for (int r = 0; r < 8; ++r) {
      const float ore = shflx(re[r], mask);
      const float oim = shflx(im[r], mask);
      re[r] = cc ? ore : re[r];
      im[r] = cc ? oim : im[r];
    }
  }
}

// ---------------------------------------------------------------------------
// Precompute cos/sin of q_w/2 (batch-independent, 36 pairs) into d_ws.
// ---------------------------------------------------------------------------
__global__ void precompute_trig(const float* __restrict__ qw, float* __restrict__ cs) {
  const int i = threadIdx.x;
  if (i < 36) {
    float s, c;
    sincosf(0.5f * qw[i], &s, &c);
    cs[2 * i]     = c;
    cs[2 * i + 1] = s;
  }
}

// ---------------------------------------------------------------------------
// Fused kernel: one wave per batch row.
//   load x row -> 8 dots (w_in) -> tanh -> LayerNorm -> circuit -> <Z_i>
//   -> out = x + b_out + qz @ w_out^T
// ---------------------------------------------------------------------------
__global__ __launch_bounds__(256, 4)
void quantum_fused(const float* __restrict__ x,
                   const float* __restrict__ w_in,
                   const float* __restrict__ b_in,
                   const float* __restrict__ gamma,
                   const float* __restrict__ beta,
                   const float* __restrict__ w_out,
                   const float* __restrict__ b_out,
                   const float* __restrict__ cs,
                   float* __restrict__ out) {
  const int lane = threadIdx.x & 63;
  const int wv   = threadIdx.x >> 6;
  const int row  = blockIdx.x * 4 + wv;

  const float* xrow = x + (size_t)row * DIM;
  const float4* xv  = (const float4*)xrow;

  // ---- load x row (stays in regs for residual): 3 float4 per lane ----
  float4 xr[3];
#pragma unroll
  for (int k = 0; k < 3; ++k) xr[k] = xv[lane + 64 * k];

  // ---- input projection: 8 dots of length 768 ----
  float h[8];
#pragma unroll
  for (int q = 0; q < 8; ++q) {
    const float4* wq = (const float4*)(w_in + q * DIM);
    float acc = 0.f;
#pragma unroll
    for (int k = 0; k < 3; ++k) {
      const float4 w4 = wq[lane + 64 * k];
      acc += xr[k].x * w4.x + xr[k].y * w4.y + xr[k].z * w4.z + xr[k].w * w4.w;
    }
    h[q] = acc;
  }
  // butterfly allreduce: every lane gets all 8 sums
#pragma unroll
  for (int m = 1; m < 64; m <<= 1) {
#pragma unroll
    for (int q = 0; q < 8; ++q) h[q] += shflx(h[q], m);
  }

  // ---- bias + tanh + LayerNorm ----
#pragma unroll
  for (int q = 0; q < 8; ++q) h[q] = tanhf(h[q] + b_in[q]);
  float mu = 0.f;
#pragma unroll
  for (int q = 0; q < 8; ++q) mu += h[q];
  mu *= 0.125f;
  float var = 0.f;
#pragma unroll
  for (int q = 0; q < 8; ++q) { const float d = h[q] - mu; var += d * d; }
  var *= 0.125f;
  const float inv = 1.0f / sqrtf(var + EPSLN);
  float ang[8];
#pragma unroll
  for (int q = 0; q < 8; ++q)
    ang[q] = (h[q] - mu) * inv * gamma[q] + beta[q];

  // ---- circuit: state in registers ----
  float re[8], im[8];
#pragma unroll
  for (int r = 0; r < 8; ++r) { re[r] = 0.f; im[r] = 0.f; }
  re[0] = (lane == 0) ? 1.f : 0.f;

  // encoding: RX(ang[i]) then RZ(ang[i]) on wire i
#define ENC_I(i) { float s_, c_; sincosf(0.5f * ang[i], &s_, &c_);            \
                   gate_rx<i>(re, im, c_, s_);                                 \
                   gate_rz<i>(re, im, c_, s_, lane); }
  ENC_I(0) ENC_I(1) ENC_I(2) ENC_I(3) ENC_I(4) ENC_I(5) ENC_I(6) ENC_I(7)
#undef ENC_I

  // layer-0 weights: RX(w[0,i]) then RZ(w[1,i]) on wire i
#define L0_I(i) { gate_rx<i>(re, im, cs[2*(i)], cs[2*(i)+1]);                  \
                  gate_rz<i>(re, im, cs[2*(9+(i))], cs[2*(9+(i))+1], lane); }
  L0_I(0) L0_I(1) L0_I(2) L0_I(3) L0_I(4) L0_I(5) L0_I(6) L0_I(7)
#undef L0_I

  // layers 1..3: CNOT(i, i+1 mod 8); RY(w[l,i]); RZ(w[l,i]); then CNOT(7,8); RY(w[l,8])
#define LSTEP(l, i, j) { gate_cnot<i, j>(re, im, lane);                        \
                         const float c_ = cs[2*((l)*9+(i))];                   \
                         const float s_ = cs[2*((l)*9+(i))+1];                 \
                         gate_ry<i>(re, im, c_, s_, lane);                     \
                         gate_rz<i>(re, im, c_, s_, lane); }
#define LAYER(l)                                                               \
  LSTEP(l,0,1) LSTEP(l,1,2) LSTEP(l,2,3) LSTEP(l,3,4)                          \
  LSTEP(l,4,5) LSTEP(l,5,6) LSTEP(l,6,7) LSTEP(l,7,0)                          \
  { gate_cnot<7, 8>(re, im, lane);                                             \
    gate_ry<8>(re, im, cs[2*((l)*9+8)], cs[2*((l)*9+8)+1], lane); }
  LAYER(1) LAYER(2) LAYER(3)
#undef LAYER
#undef LSTEP

  // ---- measurement: z[i] = P(bit_i=0) - P(bit_i=1) for wires 0..7 ----
  float p[8];
#pragma unroll
  for (int r = 0; r < 8; ++r) p[r] = re[r] * re[r] + im[r] * im[r];
  float ptot = 0.f;
#pragma unroll
  for (int r = 0; r < 8; ++r) ptot += p[r];
  float z[8];
#pragma unroll
  for (int i = 0; i < 3; ++i) {
    float acc = 0.f;
#pragma unroll
    for (int r = 0; r < 8; ++r) acc += ((r >> i) & 1) ? -p[r] : p[r];
    z[i] = acc;
  }
#pragma unroll
  for (int i = 3; i < 8; ++i)
    z[i] = ((lane >> (i - 3)) & 1) ? -ptot : ptot;
#pragma unroll
  for (int m = 1; m < 64; m <<= 1) {
#pragma unroll
    for (int i = 0; i < 8; ++i) z[i] += shflx(z[i], m);
  }

  // ---- output projection + residual: out[j] = x[j] + b_out[j] + sum_q z[q]*w_out[j,q] ----
  float* orow = out + (size_t)row * DIM;
  float4* ov = (float4*)orow;
  const float4* bv = (const float4*)b_out;
#pragma unroll
  for (int k = 0; k < 3; ++k) {
    const int j4 = lane + 64 * k;            // float4 index; element j = 4*j4
    const float4 b4 = bv[j4];
    const float4* wo = (const float4*)(w_out + (size_t)j4 * 32);  // 4 rows x 8 floats
    const float4 r0a = wo[0], r0b = wo[1];
    const float4 r1a = wo[2], r1b = wo[3];
    const float4 r2a = wo[4], r2b = wo[5];
    const float4 r3a = wo[6], r3b = wo[7];
    float4 o;
    o.x = xr[k].x + b4.x + z[0]*r0a.x + z[1]*r0a.y + z[2]*r0a.z + z[3]*r0a.w
                        + z[4]*r0b.x + z[5]*r0b.y + z[6]*r0b.z + z[7]*r0b.w;
    o.y = xr[k].y + b4.y + z[0]*r1a.x + z[1]*r1a.y + z[2]*r1a.z + z[3]*r1a.w
                        + z[4]*r1b.x + z[5]*r1b.y + z[6]*r1b.z + z[7]*r1b.w;
    o.z = xr[k].z + b4.z + z[0]*r2a.x + z[1]*r2a.y + z[2]*r2a.z + z[3]*r2a.w
                        + z[4]*r2b.x + z[5]*r2b.y + z[6]*r2b.z + z[7]*r2b.w;
    o.w = xr[k].w + b4.w + z[0]*r3a.x + z[1]*r3a.y + z[2]*r3a.z + z[3]*r3a.w
                        + z[4]*r3b.x + z[5]*r3b.y + z[6]*r3b.z + z[7]*r3b.w;
    ov[j4] = o;
  }
}

extern "C" void kernel_launch(void* const* d_in, const int* in_sizes, int n_in,
                              void* d_out, int out_size, void* d_ws, size_t ws_size,
                              hipStream_t stream) {
  const float* x     = (const float*)d_in[0];
  const float* w_in  = (const float*)d_in[1];
  const float* b_in  = (const float*)d_in[2];
  const float* gamma = (const float*)d_in[3];
  const float* beta  = (const float*)d_in[4];
  const float* q_w   = (const float*)d_in[5];
  const float* w_out = (const float*)d_in[6];
  const float* b_out = (const float*)d_in[7];
  float* outp = (float*)d_out;
  float* cs   = (float*)d_ws;   // 72 floats: (cos, sin) of q_w/2

  hipLaunchKernelGGL(precompute_trig, dim3(1), dim3(64), 0, stream, q_w, cs);
  hipLaunchKernelGGL(quantum_fused, dim3(BATCH / 4), dim3(256), 0, stream,
                     x, w_in, b_in, gamma, beta, w_out, b_out, cs, outp);
}